// Round 18
// baseline (3062.629 us; speedup 1.0000x reference)
//
#include <hip/hip_runtime.h>
#include <cstdint>
#include <cstddef>

typedef _Float16 half8  __attribute__((ext_vector_type(8)));
typedef float    floatx4 __attribute__((ext_vector_type(4)));
typedef unsigned long long ull;

#define B_  64
#define T_  512
#define D_  512
#define H_  512

static __device__ __forceinline__ float fast_sigmoid(float x) {
  return 1.0f / (1.0f + __expf(-x));
}
static __device__ __forceinline__ float fast_tanh(float x) {
  x = fminf(15.0f, fmaxf(-15.0f, x));
  float e = __expf(2.0f * x);
  return (e - 1.0f) / (e + 1.0f);
}

// LDS-only barrier: drains lgkmcnt but NOT vmcnt (global ops stay in flight).
#define LDS_BARRIER() do {                                   \
    asm volatile("s_waitcnt lgkmcnt(0)" ::: "memory");       \
    __builtin_amdgcn_s_barrier();                            \
  } while (0)

#define TAGMASK 0x0000FFFF0000FFFFull

// ---------------------------------------------------------------------------
// Single persistent kernel, v18 = R15 scan (proven: 640-stride LDS, serial
//   masked-retry poll, early publish) + proj fused into the poll's first-
//   sweep round-trip with BOTH-SIDES sched_barrier pinning:
//     issue loads | SB(0) | proj MFMA + x staging | SB(0) | tag check
//   so the compiler's vmcnt wait lands AFTER the shadow work (R17's defect:
//   only the leading SB was present, check+wait floated before the shadow).
//   xs double-buffered; XG workspace eliminated; sync fabric byte-identical
//   to R9/R13/R15 (tagged words, compiler-emitted agent atomics).
// ---------------------------------------------------------------------------
__global__ __launch_bounds__(256) void scan_kernel(
    const float* __restrict__ x,
    const float* __restrict__ Wc, const float* __restrict__ Wi,
    const float* __restrict__ Wf, const float* __restrict__ Wo,
    const float* __restrict__ Uc, const float* __restrict__ Ui,
    const float* __restrict__ Uf, const float* __restrict__ Uo,
    const float* __restrict__ bc, const float* __restrict__ bi,
    const float* __restrict__ bf2, const float* __restrict__ bo,
    float* __restrict__ out, unsigned* __restrict__ dbuf)
{
  __shared__ _Float16 h_lds[16*640];   // [ks(16)][row(16)][40 pad] = 20 KB
  __shared__ _Float16 xsA[16*640];     // x slice, even buffer
  __shared__ _Float16 xsB[16*640];     // x slice, odd buffer

  int tid = threadIdx.x;
  int grp = blockIdx.x & 7;
  int member = blockIdx.x >> 3;

  int lane = tid & 63;
  int w    = tid >> 6;            // wave = n-tile (4 cols x 4 gates)
  int c16  = lane & 15;           // n within tile = jjl*4 + g
  int sub  = lane >> 4;           // k-subchunk (input) / row-group (output)
  int g    = c16 & 3;
  int jjl  = c16 >> 2;
  int jcol = member*16 + w*4 + jjl;   // output column j
  int hi   = sub;                      // C row group: batches hi*4+i
  bool pub = (g == 0) && (hi < 2);

  // ---- one-time: U and W fragments -> VGPRs (B-frag convention) ----
  const float* Ug    = (g==0) ? Uc : (g==1) ? Ui : (g==2) ? Uf : Uo;
  const float* Wg    = (g==0) ? Wc : (g==1) ? Wi : (g==2) ? Wf : Wo;
  const float* biasg = (g==0) ? bc : (g==1) ? bi : (g==2) ? bf2 : bo;
  float bvs = biasg[jcol];

  half8 uf[16], wf[16];
  #pragma unroll
  for (int ks = 0; ks < 16; ++ks) {
    half8 vu, vw;
    #pragma unroll
    for (int q = 0; q < 8; ++q) {
      vu[q] = (_Float16)Ug[(size_t)(ks*32 + sub*8 + q) * H_ + jcol];
      vw[q] = (_Float16)Wg[(size_t)(ks*32 + sub*8 + q) * H_ + jcol];
    }
    uf[ks] = vu;
    wf[ks] = vw;
  }

  // h staging: thread's 16 polled words = h[b=sb][k=sm*16..+16)
  int sm  = tid >> 3;
  int sb  = tid & 7;
  _Float16* stg = &h_lds[(sm >> 1)*640 + sb*40 + (sm & 1)*16];

  int fragoff = c16*40 + sub*8;
  const _Float16* abase = &h_lds[fragoff];

  // x staging: thread loads x[batch xr][d = xc*16 .. +16) as 4x float4
  int xr = tid >> 5;
  int xc = tid & 31;
  const float* xrow = x + (size_t)(grp*8 + xr) * T_ * D_ + (size_t)xc*16;
  int xoff = (xc >> 1)*640 + xr*40 + (xc & 1)*16;

  float4 xr4[4];
  #define LD_X(tt) do {                                                   \
    const float4* p_ = (const float4*)(xrow + (size_t)(tt)*D_);           \
    xr4[0] = p_[0]; xr4[1] = p_[1]; xr4[2] = p_[2]; xr4[3] = p_[3];       \
  } while (0)
  #define ST_X(dst_) do {                                                 \
    half8 v0_, v1_;                                                       \
    v0_[0]=(_Float16)xr4[0].x; v0_[1]=(_Float16)xr4[0].y;                 \
    v0_[2]=(_Float16)xr4[0].z; v0_[3]=(_Float16)xr4[0].w;                 \
    v0_[4]=(_Float16)xr4[1].x; v0_[5]=(_Float16)xr4[1].y;                 \
    v0_[6]=(_Float16)xr4[1].z; v0_[7]=(_Float16)xr4[1].w;                 \
    v1_[0]=(_Float16)xr4[2].x; v1_[1]=(_Float16)xr4[2].y;                 \
    v1_[2]=(_Float16)xr4[2].z; v1_[3]=(_Float16)xr4[2].w;                 \
    v1_[4]=(_Float16)xr4[3].x; v1_[5]=(_Float16)xr4[3].y;                 \
    v1_[6]=(_Float16)xr4[3].z; v1_[7]=(_Float16)xr4[3].w;                 \
    *(half8*)((dst_) + xoff)      = v0_;                                  \
    *(half8*)((dst_) + xoff + 8)  = v1_;                                  \
  } while (0)

  #define PROJ_MFMA(src_, dst4_) do {                                    \
    floatx4 p0_ = {bvs, bvs, bvs, bvs}, p1_ = {0.f, 0.f, 0.f, 0.f};      \
    const _Float16* pb_ = (src_) + fragoff;                               \
    _Pragma("unroll")                                                     \
    for (int ks_ = 0; ks_ < 16; ks_ += 2) {                               \
      half8 f0_ = *(const half8*)(pb_ + ks_*640);                         \
      p0_ = __builtin_amdgcn_mfma_f32_16x16x32_f16(f0_, wf[ks_],   p0_, 0, 0, 0); \
      half8 f1_ = *(const half8*)(pb_ + (ks_+1)*640);                     \
      p1_ = __builtin_amdgcn_mfma_f32_16x16x32_f16(f1_, wf[ks_+1], p1_, 0, 0, 0); \
    }                                                                     \
    _Pragma("unroll")                                                     \
    for (int i_ = 0; i_ < 4; ++i_) (dst4_)[i_] = p0_[i_] + p1_[i_];       \
  } while (0)

  // ---- prologue: xgc(t=0) from x(0); xsB = x(1); regs = x(2) ----
  LD_X(0);  ST_X(xsA);  __syncthreads();
  float xgc[4];
  PROJ_MFMA(xsA, xgc);
  LD_X(1);  ST_X(xsB);  __syncthreads();
  LD_X(2);

  floatx4 c4 = {0.f, 0.f, 0.f, 0.f};

  for (int t = 0; t < T_; ++t) {
    LDS_BARRIER();   // prev step's h/xs frag reads complete before overwrite

    float xgn[4];
    // ---- poll h^t with proj + xs staging pinned INSIDE the first-sweep RT ----
    {
      const ull* src8 = (const ull*)dbuf
          + ((size_t)(t & 1))*16384u + (size_t)grp*2048u + (size_t)tid*8u;
      ull want2 = (ull)(unsigned)(t & 0xFFFF) * 0x0000000100000001ull;
      ull w8[8];
      // issue the sweep
      #pragma unroll
      for (int q = 0; q < 8; ++q)
        w8[q] = __hip_atomic_load(src8 + q, __ATOMIC_RELAXED,
                                  __HIP_MEMORY_SCOPE_AGENT);
      __builtin_amdgcn_sched_barrier(0);   // loads pinned BEFORE shadow

      // shadow work (independent of w8): proj MFMA for t+1 from xs[(t+1)&1],
      // stage x(t+2) into xs[t&1] from regs loaded last step
      {
        const _Float16* psrc = ((t + 1) & 1) ? xsB : xsA;
        _Float16*       pdst = (t & 1) ? xsB : xsA;
        PROJ_MFMA(psrc, xgn);
        ST_X(pdst);
      }
      __builtin_amdgcn_sched_barrier(0);   // check (and its vmcnt) AFTER shadow

      // tag check + masked retry (R13-proven)
      unsigned pend = 0;
      #pragma unroll
      for (int q = 0; q < 8; ++q)
        if ((w8[q] ^ want2) & TAGMASK) pend |= 1u << q;
      while (pend) {
        __builtin_amdgcn_s_sleep(2);
        #pragma unroll
        for (int q = 0; q < 8; ++q)
          if (pend & (1u << q))
            w8[q] = __hip_atomic_load(src8 + q, __ATOMIC_RELAXED,
                                      __HIP_MEMORY_SCOPE_AGENT);
        unsigned npend = 0;
        #pragma unroll
        for (int q = 0; q < 8; ++q)
          if ((pend & (1u << q)) && ((w8[q] ^ want2) & TAGMASK))
            npend |= 1u << q;
        pend = npend;
      }
      half8 hv0, hv1;
      #pragma unroll
      for (int q = 0; q < 4; ++q) {
        hv0[2*q]   = __builtin_bit_cast(_Float16, (unsigned short)((unsigned)w8[q]   >> 16));
        hv0[2*q+1] = __builtin_bit_cast(_Float16, (unsigned short)(w8[q]   >> 48));
        hv1[2*q]   = __builtin_bit_cast(_Float16, (unsigned short)((unsigned)w8[4+q] >> 16));
        hv1[2*q+1] = __builtin_bit_cast(_Float16, (unsigned short)(w8[4+q] >> 48));
      }
      *(half8*)stg       = hv0;
      *(half8*)(stg + 8) = hv1;
    }
    LDS_BARRIER();   // staged h visible; xs[t&1] safe to read next step

    // ---- recurrence MFMA: acc[b][c16] = sum_k h[b][k] * U[k][col] ----
    floatx4 a0 = {0.f,0.f,0.f,0.f}, a1 = {0.f,0.f,0.f,0.f};
    #pragma unroll
    for (int ks = 0; ks < 16; ks += 2) {
      half8 af0 = *(const half8*)(abase + ks*640);
      a0 = __builtin_amdgcn_mfma_f32_16x16x32_f16(af0, uf[ks],   a0, 0, 0, 0);
      half8 af1 = *(const half8*)(abase + (ks+1)*640);
      a1 = __builtin_amdgcn_mfma_f32_16x16x32_f16(af1, uf[ks+1], a1, 0, 0, 0);
    }

    // ---- gates + EARLY publish (critical path) ----
    float hval[4];
    #pragma unroll
    for (int i = 0; i < 4; ++i) {
      float pre = (a0[i] + a1[i]) + xgc[i];
      float act = (g == 0) ? fast_tanh(pre) : fast_sigmoid(pre);
      float t1  = __shfl_xor(act, 1);    // g0 <- sig(i)
      float ia  = act * t1;              // g0: tanh(a)*sig(i)
      float fv  = __shfl_xor(act, 2);    // g0 <- sig(f)
      float ov  = __shfl_xor(t1, 2);     // g0 <- sig(o)
      float cn  = fmaf(fv, c4[i], ia);
      c4[i] = cn;
      float hv = ov * fast_tanh(cn);
      hval[i] = hv;
      if (pub && (t + 1 < T_)) {
        unsigned wv = ((unsigned)__builtin_bit_cast(unsigned short,
                            (_Float16)hv) << 16)
                    | ((unsigned)(t + 1) & 0xFFFFu);
        unsigned widx = ((unsigned)((t + 1) & 1))*32768u + (unsigned)grp*4096u
                      + (unsigned)member*128u
                      + (unsigned)((hi*4 + i)*16 + w*4 + jjl);
        __hip_atomic_store(&dbuf[widx], wv,
                           __ATOMIC_RELAXED, __HIP_MEMORY_SCOPE_AGENT);
      }
    }

    // ---- out stores (poll shadow of next step) ----
    if (pub) {
      #pragma unroll
      for (int i = 0; i < 4; ++i)
        out[((size_t)(grp*8 + hi*4 + i) * T_ + t) * H_ + jcol] = hval[i];
    }

    xgc[0] = xgn[0]; xgc[1] = xgn[1]; xgc[2] = xgn[2]; xgc[3] = xgn[3];

    // ---- issue x loads for t+3 (land during next poll) ----
    {
      int xt = (t + 3 < T_) ? (t + 3) : (T_ - 1);
      LD_X(xt);
    }
  }
}

// ---------------------------------------------------------------------------
extern "C" void kernel_launch(void* const* d_in, const int* in_sizes, int n_in,
                              void* d_out, int out_size, void* d_ws, size_t ws_size,
                              hipStream_t stream)
{
  const float* x  = (const float*)d_in[0];
  const float* Wc = (const float*)d_in[1];
  const float* Wi = (const float*)d_in[2];
  const float* Wf = (const float*)d_in[3];
  const float* Wo = (const float*)d_in[4];
  const float* Uc = (const float*)d_in[5];
  const float* Ui = (const float*)d_in[6];
  const float* Uf = (const float*)d_in[7];
  const float* Uo = (const float*)d_in[8];
  const float* bc = (const float*)d_in[9];
  const float* bi = (const float*)d_in[10];
  const float* bf2= (const float*)d_in[11];
  const float* bo = (const float*)d_in[12];
  float* out = (float*)d_out;

  const size_t DB_BYTES = (size_t)2 * 8 * 4096 * sizeof(unsigned);  // 256 KiB

  if (ws_size < DB_BYTES) return;

  unsigned* dbuf = (unsigned*)d_ws;

  // tag 0 == "h^0 = 0 ready"; re-zeroed every launch (kills replay aliasing)
  (void)hipMemsetAsync(dbuf, 0, DB_BYTES, stream);

  scan_kernel<<<dim3(256), dim3(256), 0, stream>>>(
      x, Wc, Wi, Wf, Wo, Uc, Ui, Uf, Uo, bc, bi, bf2, bo, out, dbuf);
}

// Round 19
// 2060.701 us; speedup vs baseline: 1.4862x; 1.4862x over previous
//
#include <hip/hip_runtime.h>
#include <cstdint>
#include <cstddef>

typedef _Float16 half8  __attribute__((ext_vector_type(8)));
typedef float    floatx4 __attribute__((ext_vector_type(4)));
typedef unsigned long long ull;

#define B_  64
#define T_  512
#define D_  512
#define H_  512
#define NG  2048   // 4*H

static __device__ __forceinline__ float fast_sigmoid(float x) {
  return 1.0f / (1.0f + __expf(-x));
}
static __device__ __forceinline__ float fast_tanh(float x) {
  x = fminf(15.0f, fmaxf(-15.0f, x));
  float e = __expf(2.0f * x);
  return (e - 1.0f) / (e + 1.0f);
}

// LDS-only barrier: drains lgkmcnt but NOT vmcnt (global ops stay in flight).
#define LDS_BARRIER() do {                                   \
    asm volatile("s_waitcnt lgkmcnt(0)" ::: "memory");       \
    __builtin_amdgcn_s_barrier();                            \
  } while (0)

#define TAGMASK 0x0000FFFF0000FFFFull

// ---------------------------------------------------------------------------
// Kernel 1: input projections (MFMA f16, ~0.17 ms)
// ---------------------------------------------------------------------------
__global__ __launch_bounds__(256) void proj_kernel(
    const float* __restrict__ x,
    const float* __restrict__ Wc, const float* __restrict__ Wi,
    const float* __restrict__ Wf, const float* __restrict__ Wo,
    const float* __restrict__ bc, const float* __restrict__ bi,
    const float* __restrict__ bf2, const float* __restrict__ bo,
    _Float16* __restrict__ XG)
{
  const int tiles_n = NG / 64;
  int tM = blockIdx.x / tiles_n;
  int tN = blockIdx.x % tiles_n;
  int r0 = tM * 64;
  int t0 = r0 >> 6;
  int n0 = tN * 64;
  int g  = n0 >> 9;
  const float* W    = (g==0) ? Wc : (g==1) ? Wi : (g==2) ? Wf : Wo;
  const float* bias = (g==0) ? bc : (g==1) ? bi : (g==2) ? bf2 : bo;
  int j0 = n0 & (H_-1);

  __shared__ _Float16 Al[64*40];
  __shared__ _Float16 Bl[64*40];

  int tid  = threadIdx.x;
  int wave = tid >> 6;
  int lane = tid & 63;

  floatx4 acc[4] = {};

  int arow = tid >> 2;
  int ak0  = (tid & 3) * 8;
  const float* xsrc = x + ((size_t)arow * T_ + t0) * D_;

  int bcol = tid & 63;
  int bk0  = (tid >> 6) * 8;

  for (int k0 = 0; k0 < D_; k0 += 32) {
    half8 av;
    #pragma unroll
    for (int i = 0; i < 8; ++i) av[i] = (_Float16)xsrc[k0 + ak0 + i];
    *(half8*)&Al[arow*40 + ak0] = av;

    half8 bv;
    #pragma unroll
    for (int i = 0; i < 8; ++i)
      bv[i] = (_Float16)W[(size_t)(k0 + bk0 + i) * H_ + j0 + bcol];
    *(half8*)&Bl[bcol*40 + bk0] = bv;

    __syncthreads();

    half8 afrag = *(half8*)&Al[(wave*16 + (lane & 15))*40 + (lane >> 4)*8];
    #pragma unroll
    for (int ct = 0; ct < 4; ++ct) {
      half8 bfrag = *(half8*)&Bl[(ct*16 + (lane & 15))*40 + (lane >> 4)*8];
      acc[ct] = __builtin_amdgcn_mfma_f32_16x16x32_f16(afrag, bfrag, acc[ct], 0, 0, 0);
    }
    __syncthreads();
  }

  #pragma unroll
  for (int ct = 0; ct < 4; ++ct) {
    int col = n0 + ct*16 + (lane & 15);
    float bvs = bias[col & (H_-1)];
    #pragma unroll
    for (int i = 0; i < 4; ++i) {
      int row = r0 + wave*16 + (lane >> 4)*4 + i;
      XG[(size_t)row * NG + col] = (_Float16)(acc[ct][i] + bvs);
    }
  }
}

// ---------------------------------------------------------------------------
// Kernel 2: persistent scan (best-known: R15) — R13 poll + padded LDS +
//   early per-i publish. Sync fabric: tagged words (f16 h << 16 | step tag),
//   compiler-emitted agent atomics, masked retry + backoff. Step floor
//   ~3.7 µs = MALL publish-visibility + discovery + compute; confirmed by
//   R7/R10/R11/R12/R14/R16-18 falsifications.
// ---------------------------------------------------------------------------
__global__ __launch_bounds__(256) void scan_kernel(
    const _Float16* __restrict__ XG,
    const float* __restrict__ Uc, const float* __restrict__ Ui,
    const float* __restrict__ Uf, const float* __restrict__ Uo,
    float* __restrict__ out, unsigned* __restrict__ dbuf)
{
  __shared__ _Float16 h_lds[16*640];   // [ks(16)][row(16)][40 pad] = 20 KB

  int tid = threadIdx.x;
  int grp = blockIdx.x & 7;
  int member = blockIdx.x >> 3;

  int lane = tid & 63;
  int w    = tid >> 6;            // wave = n-tile (4 cols x 4 gates)
  int c16  = lane & 15;           // n within tile = jjl*4 + g
  int sub  = lane >> 4;           // k-subchunk (input) / row-group (output)
  int g    = c16 & 3;
  int jjl  = c16 >> 2;
  int jcol = member*16 + w*4 + jjl;   // output column j
  int hi   = sub;                      // C row group: batches hi*4+i
  bool pub = (g == 0) && (hi < 2);

  // ---- one-time: U fragments -> VGPRs (B-frag: lane holds B[col][k8]) ----
  const float* Ug = (g==0) ? Uc : (g==1) ? Ui : (g==2) ? Uf : Uo;
  half8 uf[16];
  #pragma unroll
  for (int ks = 0; ks < 16; ++ks) {
    half8 v;
    #pragma unroll
    for (int q = 0; q < 8; ++q)
      v[q] = (_Float16)Ug[(size_t)(ks*32 + sub*8 + q) * H_ + jcol];
    uf[ks] = v;
  }

  // consumer staging: thread's 16 polled words = h[b=sb][k=sm*16..+16)
  int sm  = tid >> 3;             // source member
  int sb  = tid & 7;              // batch row
  _Float16* stg = &h_lds[(sm >> 1)*640 + sb*40 + (sm & 1)*16];

  const _Float16* abase = &h_lds[c16*40 + sub*8];   // + ks*640 per k-step

  floatx4 c4 = {0.f, 0.f, 0.f, 0.f};
  float xg[4] = {0.f, 0.f, 0.f, 0.f};
  #pragma unroll
  for (int i = 0; i < 4; ++i)
    if (hi < 2)
      xg[i] = (float)XG[(size_t)(grp*8 + hi*4 + i) * NG + g*512 + jcol];

  for (int t = 0; t < T_; ++t) {
    LDS_BARRIER();   // prev step's A-frag reads complete before overwrite

    // ---- poll h^t (R13-proven: bulk read + masked retry + backoff) ----
    {
      const ull* src8 = (const ull*)dbuf
          + ((size_t)(t & 1))*16384u + (size_t)grp*2048u + (size_t)tid*8u;
      ull want2 = (ull)(unsigned)(t & 0xFFFF) * 0x0000000100000001ull;
      ull w8[8];
      unsigned pend = 0xFFu;
      for (;;) {
        #pragma unroll
        for (int q = 0; q < 8; ++q)
          if (pend & (1u << q))
            w8[q] = __hip_atomic_load(src8 + q, __ATOMIC_RELAXED,
                                      __HIP_MEMORY_SCOPE_AGENT);
        unsigned npend = 0;
        #pragma unroll
        for (int q = 0; q < 8; ++q)
          if ((pend & (1u << q)) && ((w8[q] ^ want2) & TAGMASK))
            npend |= 1u << q;
        if (!npend) break;
        pend = npend;
        __builtin_amdgcn_s_sleep(2);
      }
      half8 hv0, hv1;
      #pragma unroll
      for (int q = 0; q < 4; ++q) {
        hv0[2*q]   = __builtin_bit_cast(_Float16, (unsigned short)((unsigned)w8[q]   >> 16));
        hv0[2*q+1] = __builtin_bit_cast(_Float16, (unsigned short)(w8[q]   >> 48));
        hv1[2*q]   = __builtin_bit_cast(_Float16, (unsigned short)((unsigned)w8[4+q] >> 16));
        hv1[2*q+1] = __builtin_bit_cast(_Float16, (unsigned short)(w8[4+q] >> 48));
      }
      *(half8*)stg       = hv0;
      *(half8*)(stg + 8) = hv1;
    }
    LDS_BARRIER();   // staged h visible

    // ---- MFMA dot: acc[b][c16] = sum_k h[b][k] * U[k][col] ----
    floatx4 a0 = {0.f,0.f,0.f,0.f}, a1 = {0.f,0.f,0.f,0.f};
    #pragma unroll
    for (int ks = 0; ks < 16; ks += 2) {
      half8 af0 = *(const half8*)(abase + ks*640);
      a0 = __builtin_amdgcn_mfma_f32_16x16x32_f16(af0, uf[ks],   a0, 0, 0, 0);
      half8 af1 = *(const half8*)(abase + (ks+1)*640);
      a1 = __builtin_amdgcn_mfma_f32_16x16x32_f16(af1, uf[ks+1], a1, 0, 0, 0);
    }

    // ---- gates + EARLY publish (per-i, as soon as computed) ----
    float hval[4];
    #pragma unroll
    for (int i = 0; i < 4; ++i) {
      float pre = (a0[i] + a1[i]) + xg[i];
      float act = (g == 0) ? fast_tanh(pre) : fast_sigmoid(pre);
      float t1  = __shfl_xor(act, 1);    // g0 <- sig(i)
      float ia  = act * t1;              // g0: tanh(a)*sig(i)
      float fv  = __shfl_xor(act, 2);    // g0 <- sig(f)
      float ov  = __shfl_xor(t1, 2);     // g0 <- sig(o)
      float cn  = fmaf(fv, c4[i], ia);
      c4[i] = cn;
      float hv = ov * fast_tanh(cn);
      hval[i] = hv;
      if (pub && (t + 1 < T_)) {
        unsigned wv = ((unsigned)__builtin_bit_cast(unsigned short,
                            (_Float16)hv) << 16)
                    | ((unsigned)(t + 1) & 0xFFFFu);
        unsigned widx = ((unsigned)((t + 1) & 1))*32768u + (unsigned)grp*4096u
                      + (unsigned)member*128u
                      + (unsigned)((hi*4 + i)*16 + w*4 + jjl);
        __hip_atomic_store(&dbuf[widx], wv,
                           __ATOMIC_RELAXED, __HIP_MEMORY_SCOPE_AGENT);
      }
    }

    // ---- out stores (in poll shadow) ----
    if (pub) {
      #pragma unroll
      for (int i = 0; i < 4; ++i)
        out[((size_t)(grp*8 + hi*4 + i) * T_ + t) * H_ + jcol] = hval[i];
    }

    // ---- prefetch XG for t+1 (rides under next poll) ----
    if (t + 1 < T_) {
      #pragma unroll
      for (int i = 0; i < 4; ++i)
        if (hi < 2)
          xg[i] = (float)XG[((size_t)(t + 1)*B_ + grp*8 + hi*4 + i) * NG
                            + g*512 + jcol];
    }
  }
}

// ---------------------------------------------------------------------------
extern "C" void kernel_launch(void* const* d_in, const int* in_sizes, int n_in,
                              void* d_out, int out_size, void* d_ws, size_t ws_size,
                              hipStream_t stream)
{
  const float* x  = (const float*)d_in[0];
  const float* Wc = (const float*)d_in[1];
  const float* Wi = (const float*)d_in[2];
  const float* Wf = (const float*)d_in[3];
  const float* Wo = (const float*)d_in[4];
  const float* Uc = (const float*)d_in[5];
  const float* Ui = (const float*)d_in[6];
  const float* Uf = (const float*)d_in[7];
  const float* Uo = (const float*)d_in[8];
  const float* bc = (const float*)d_in[9];
  const float* bi = (const float*)d_in[10];
  const float* bf2= (const float*)d_in[11];
  const float* bo = (const float*)d_in[12];
  float* out = (float*)d_out;

  const size_t XG_BYTES = (size_t)T_ * B_ * NG * sizeof(_Float16);  // 128 MiB
  const size_t DB_BYTES = (size_t)2 * 8 * 4096 * sizeof(unsigned);  // 256 KiB

  if (ws_size < XG_BYTES + DB_BYTES) return;

  _Float16* XG   = (_Float16*)d_ws;
  unsigned* dbuf = (unsigned*)((char*)d_ws + XG_BYTES);

  // tag 0 == "h^0 = 0 ready"; re-zeroed every launch (kills replay aliasing)
  (void)hipMemsetAsync(dbuf, 0, DB_BYTES, stream);

  proj_kernel<<<dim3((T_*B_/64) * (NG/64)), dim3(256), 0, stream>>>(
      x, Wc, Wi, Wf, Wo, bc, bi, bf2, bo, XG);

  scan_kernel<<<dim3(256), dim3(256), 0, stream>>>(
      XG, Uc, Ui, Uf, Uo, out, dbuf);
}